// Round 1
// baseline (1750.964 us; speedup 1.0000x reference)
//
#include <hip/hip_runtime.h>
#include <math.h>

#define Bsz 32
#define Lseq 1024
#define NTOK (Bsz*Lseq)          // 32768
#define DIN 256                  // D_INNER
#define CHUNK 64
#define NCHUNK 16

// ---------------- precompute: folded weight products ----------------
// Minp = w_inproj @ w_proj  (512x12), cinp = w_inproj @ b_proj (512)
// M2   = w_ih @ w_out       (512x256), c2 = b_ih + b_hh (512)
// Ab   = -exp(A_log)        (256x16)
__global__ void k_pre(const float* w_proj, const float* b_proj, const float* w_inproj,
                      const float* A_log, const float* w_ih, const float* w_out,
                      const float* b_ih, const float* b_hh,
                      float* Ab, float* Minp, float* cinp, float* M2, float* c2) {
    int idx = blockIdx.x * 256 + threadIdx.x;
    if (idx < 4096) {
        Ab[idx] = -expf(A_log[idx]);
    } else if (idx < 4096 + 6144) {
        int j = idx - 4096; int o = j / 12; int i = j - o * 12;
        float s = 0.f;
        for (int k = 0; k < 128; ++k) s += w_inproj[o*128+k] * w_proj[k*12+i];
        Minp[j] = s;
    } else if (idx < 4096 + 6144 + 512) {
        int o = idx - (4096 + 6144);
        float s = 0.f;
        for (int k = 0; k < 128; ++k) s += w_inproj[o*128+k] * b_proj[k];
        cinp[o] = s;
    } else if (idx < 4096 + 6144 + 512 + 131072) {
        int j = idx - (4096 + 6144 + 512);
        int o = j >> 8; int dd = j & 255;
        float s = 0.f;
        for (int k = 0; k < 128; ++k) s += w_ih[o*128+k] * w_out[k*256+dd];
        M2[j] = s;
    } else if (idx < 4096 + 6144 + 512 + 131072 + 512) {
        int o = idx - (4096 + 6144 + 512 + 131072);
        c2[o] = b_ih[o] + b_hh[o];
    }
}

// ---------------- k1: xz = x @ Minp^T + cinp, split u0 / z ----------------
__global__ void k_inproj(const float* __restrict__ x, const float* __restrict__ Minp,
                         const float* __restrict__ cinp,
                         float* __restrict__ u0, float* __restrict__ zb) {
    int gid = blockIdx.x * 256 + threadIdx.x;      // 16,777,216
    int tok = gid >> 9;
    int o = gid & 511;
    const float* xr = x + tok * 12;
    const float* mr = Minp + o * 12;
    float acc = cinp[o];
#pragma unroll
    for (int i = 0; i < 12; ++i) acc += xr[i] * mr[i];
    if (o < 256) u0[tok*256 + o] = acc;
    else         zb[tok*256 + (o - 256)] = acc;
}

// ---------------- k2: depthwise causal conv (K=4) + SiLU ----------------
__global__ void k_conv(const float* __restrict__ u0, const float* __restrict__ conv_w,
                       const float* __restrict__ conv_b, float* __restrict__ uc) {
    int gid = blockIdx.x * 256 + threadIdx.x;      // 8,388,608
    int d = gid & 255;
    int tok = gid >> 8;
    int t = tok & 1023;
    int b = tok >> 10;
    float acc = conv_b[d];
#pragma unroll
    for (int k = 0; k < 4; ++k) {
        int tt = t + k - 3;
        if (tt >= 0) acc += conv_w[d*4+k] * u0[(b*1024+tt)*256 + d];
    }
    acc = acc / (1.f + __expf(-acc));   // silu
    uc[gid] = acc;
}

// ---------------- k3: xdbc = uc @ w_xproj^T; dt = softplus(xdbc[:8]@w_dt^T+b_dt) ----------------
__global__ void __launch_bounds__(256) k_xproj(const float* __restrict__ uc,
                        const float* __restrict__ w_xproj, const float* __restrict__ w_dt,
                        const float* __restrict__ b_dt,
                        float* __restrict__ dtb, float* __restrict__ Bm, float* __restrict__ Cm) {
    __shared__ float ur[256];
    __shared__ float xd[40];
    int tok = blockIdx.x;
    int tid = threadIdx.x;
    ur[tid] = uc[tok*256 + tid];
    __syncthreads();
    // 40 outputs, each split over 4 lanes (64-element partial dots)
    int j = tid >> 2, q = tid & 3;
    float s = 0.f;
    if (j < 40) {
        const float* wr = w_xproj + j*256 + q*64;
        const float* uq = ur + q*64;
#pragma unroll 8
        for (int k = 0; k < 64; ++k) s += wr[k] * uq[k];
    }
    s += __shfl_xor(s, 1);
    s += __shfl_xor(s, 2);
    if (j < 40 && q == 0) {
        xd[j] = s;
        if (j >= 8 && j < 24)      Bm[tok*16 + (j - 8)]  = s;
        else if (j >= 24)          Cm[tok*16 + (j - 24)] = s;
    }
    __syncthreads();
    float r = b_dt[tid];
    const float* wd = w_dt + tid*8;
#pragma unroll
    for (int jj = 0; jj < 8; ++jj) r += wd[jj] * xd[jj];
    r = (r > 20.f) ? r : log1pf(expf(r));   // softplus
    dtb[tok*256 + tid] = r;
}

// ---------------- SSM chunked scan ----------------
// phase 1: per (b,chunk,d): zero-init end state h0end[16] and S = sum(dt)
__global__ void __launch_bounds__(256) k_ssm_p1(const float* __restrict__ dtb,
                        const float* __restrict__ uc, const float* __restrict__ Bm,
                        const float* __restrict__ Ab,
                        float* __restrict__ h0end, float* __restrict__ Ssum) {
    __shared__ float Bs[CHUNK*16];
    int b = blockIdx.x >> 4;
    int c = blockIdx.x & 15;
    int d = threadIdx.x;
    int t0 = c * CHUNK;
    {
        const float* src = Bm + (b*1024 + t0) * 16;
        for (int i = d; i < CHUNK*16; i += 256) Bs[i] = src[i];
    }
    __syncthreads();
    float a[16], h[16];
#pragma unroll
    for (int s = 0; s < 16; ++s) { a[s] = Ab[d*16+s]; h[s] = 0.f; }
    float S = 0.f;
    const float* dtp = dtb + (b*1024 + t0)*256 + d;
    const float* up  = uc  + (b*1024 + t0)*256 + d;
    float dtv = dtp[0], uv = up[0];
    for (int t = 0; t < CHUNK; ++t) {
        float dtn = 0.f, un = 0.f;
        if (t < CHUNK-1) { dtn = dtp[(t+1)*256]; un = up[(t+1)*256]; }
        float dtu = dtv * uv;
        S += dtv;
#pragma unroll
        for (int s = 0; s < 16; ++s) {
            float dA = __expf(dtv * a[s]);
            h[s] = h[s]*dA + dtu * Bs[t*16+s];
        }
        dtv = dtn; uv = un;
    }
    float* he = h0end + ((b*256 + d)*16 + c)*16;
#pragma unroll
    for (int s = 0; s < 16; ++s) he[s] = h[s];
    Ssum[(b*256 + d)*16 + c] = S;
}

// phase 2: scan over chunk carries; hinit[c] = carry before chunk c
__global__ void k_ssm_p2(const float* __restrict__ h0end, const float* __restrict__ Ssum,
                         const float* __restrict__ Ab, float* __restrict__ hinit) {
    int gid = blockIdx.x * 256 + threadIdx.x;   // 131072 = 32*256*16
    int s = gid & 15;
    int bd = gid >> 4;
    int d = bd & 255;
    float a = Ab[d*16 + s];
    float carry = 0.f;
    const float* he = h0end + bd * 256;
    float* hi = hinit + bd * 256;
    const float* Sp = Ssum + bd * 16;
    for (int c = 0; c < 16; ++c) {
        hi[c*16 + s] = carry;
        carry = he[c*16 + s] + __expf(a * Sp[c]) * carry;
    }
}

// phase 3: replay chunks with correct init, emit yg = (y + u*Dskip)*silu(z)
__global__ void __launch_bounds__(256) k_ssm_p3(const float* __restrict__ dtb,
                        const float* __restrict__ uc, const float* __restrict__ zb,
                        const float* __restrict__ Bm, const float* __restrict__ Cm,
                        const float* __restrict__ Ab, const float* __restrict__ Dskip,
                        const float* __restrict__ hinit, float* __restrict__ yg) {
    __shared__ float Bs[CHUNK*16];
    __shared__ float Cs[CHUNK*16];
    int b = blockIdx.x >> 4;
    int c = blockIdx.x & 15;
    int d = threadIdx.x;
    int t0 = c * CHUNK;
    {
        const float* srcB = Bm + (b*1024 + t0) * 16;
        const float* srcC = Cm + (b*1024 + t0) * 16;
        for (int i = d; i < CHUNK*16; i += 256) { Bs[i] = srcB[i]; Cs[i] = srcC[i]; }
    }
    __syncthreads();
    float a[16], h[16];
    const float* hi = hinit + ((b*256 + d)*16 + c)*16;
#pragma unroll
    for (int s = 0; s < 16; ++s) { a[s] = Ab[d*16+s]; h[s] = hi[s]; }
    float Dv = Dskip[d];
    const float* dtp = dtb + (b*1024 + t0)*256 + d;
    const float* up  = uc  + (b*1024 + t0)*256 + d;
    const float* zp  = zb  + (b*1024 + t0)*256 + d;
    float* yp = yg + (b*1024 + t0)*256 + d;
    float dtv = dtp[0], uv = up[0], zv = zp[0];
    for (int t = 0; t < CHUNK; ++t) {
        float dtn = 0.f, un = 0.f, zn = 0.f;
        if (t < CHUNK-1) { dtn = dtp[(t+1)*256]; un = up[(t+1)*256]; zn = zp[(t+1)*256]; }
        float dtu = dtv * uv;
        float y = 0.f;
#pragma unroll
        for (int s = 0; s < 16; ++s) {
            float dA = __expf(dtv * a[s]);
            h[s] = h[s]*dA + dtu * Bs[t*16+s];
            y += h[s] * Cs[t*16+s];
        }
        float sz = zv / (1.f + __expf(-zv));
        yp[t*256] = (y + uv * Dv) * sz;
        dtv = dtn; uv = un; zv = zn;
    }
}

// ---------------- k5: xg = yg @ M2^T + c2  (32768x512, K=256) ----------------
__global__ void __launch_bounds__(256) k_xg(const float* __restrict__ yg,
                      const float* __restrict__ M2, const float* __restrict__ c2,
                      float* __restrict__ xg) {
    __shared__ float ytile[16][256];
    int tokbase = blockIdx.x * 16;
    int tid = threadIdx.x;
    for (int r = 0; r < 16; ++r) ytile[r][tid] = yg[(tokbase + r)*256 + tid];
    __syncthreads();
    int o0 = tid, o1 = tid + 256;
    float acc0[16], acc1[16];
    float cc0 = c2[o0], cc1 = c2[o1];
#pragma unroll
    for (int r = 0; r < 16; ++r) { acc0[r] = cc0; acc1[r] = cc1; }
    const float4* m0 = (const float4*)(M2 + o0*256);
    const float4* m1 = (const float4*)(M2 + o1*256);
    for (int k4 = 0; k4 < 64; ++k4) {
        float4 w0 = m0[k4];
        float4 w1 = m1[k4];
#pragma unroll
        for (int r = 0; r < 16; ++r) {
            float4 v = *(const float4*)&ytile[r][k4*4];
            acc0[r] += v.x*w0.x + v.y*w0.y + v.z*w0.z + v.w*w0.w;
            acc1[r] += v.x*w1.x + v.y*w1.y + v.z*w1.z + v.w*w1.w;
        }
    }
    for (int r = 0; r < 16; ++r) {
        xg[(tokbase + r)*512 + o0] = acc0[r];
        xg[(tokbase + r)*512 + o1] = acc1[r];
    }
}

// ---------------- k6: LSTM (one block per batch) + FC head ----------------
__global__ void __launch_bounds__(512) k_lstm(const float* __restrict__ xg,
                       const float* __restrict__ w_hh,
                       const float* __restrict__ w_fc1, const float* __restrict__ b_fc1,
                       const float* __restrict__ w_fc2, const float* __restrict__ b_fc2,
                       float* __restrict__ out) {
    __shared__ float hbuf[128];
    __shared__ float gbuf[512];
    int b = blockIdx.x;
    int tid = threadIdx.x;
    // w_hh row for this thread's gate output, register-resident
    float w[128];
    const float4* wr = (const float4*)(w_hh + tid*128);
#pragma unroll
    for (int k4 = 0; k4 < 32; ++k4) {
        float4 v = wr[k4];
        w[k4*4+0] = v.x; w[k4*4+1] = v.y; w[k4*4+2] = v.z; w[k4*4+3] = v.w;
    }
    float cstate = 0.f;
    if (tid < 128) hbuf[tid] = 0.f;
    __syncthreads();
    const float* xgb = xg + (size_t)b * 1024 * 512;
    float gx = xgb[tid];
    for (int t = 0; t < 1024; ++t) {
        float gxn = (t < 1023) ? xgb[(t+1)*512 + tid] : 0.f;   // prefetch
        float g = gx;
        const float4* h4 = (const float4*)hbuf;
#pragma unroll
        for (int k4 = 0; k4 < 32; ++k4) {
            float4 hv = h4[k4];
            g += hv.x*w[k4*4] + hv.y*w[k4*4+1] + hv.z*w[k4*4+2] + hv.w*w[k4*4+3];
        }
        gbuf[tid] = g;
        __syncthreads();
        if (tid < 128) {
            float ig = 1.f/(1.f + __expf(-gbuf[tid]));
            float fg = 1.f/(1.f + __expf(-gbuf[tid+128]));
            float gg = tanhf(gbuf[tid+256]);
            float og = 1.f/(1.f + __expf(-gbuf[tid+384]));
            cstate = fg*cstate + ig*gg;
            hbuf[tid] = og * tanhf(cstate);
        }
        __syncthreads();
        gx = gxn;
    }
    // FC head: relu(h @ w_fc1^T + b_fc1) @ w_fc2^T + b_fc2
    if (tid < 128) {
        float s = b_fc1[tid];
        const float* wf = w_fc1 + tid*128;
#pragma unroll 4
        for (int k = 0; k < 128; ++k) s += wf[k] * hbuf[k];
        gbuf[tid] = fmaxf(s, 0.f);
    }
    __syncthreads();
    if (tid < 5) {
        float s = b_fc2[tid];
        const float* wf = w_fc2 + tid*128;
        for (int k = 0; k < 128; ++k) s += wf[k] * gbuf[k];
        out[b*5 + tid] = s;
    }
}

// ---------------- launch ----------------
extern "C" void kernel_launch(void* const* d_in, const int* in_sizes, int n_in,
                              void* d_out, int out_size, void* d_ws, size_t ws_size,
                              hipStream_t stream) {
    const float* x        = (const float*)d_in[0];
    const float* w_proj   = (const float*)d_in[1];
    const float* b_proj   = (const float*)d_in[2];
    const float* w_inproj = (const float*)d_in[3];
    const float* conv_w   = (const float*)d_in[4];
    const float* conv_b   = (const float*)d_in[5];
    const float* w_xproj  = (const float*)d_in[6];
    const float* w_dt     = (const float*)d_in[7];
    const float* b_dt     = (const float*)d_in[8];
    const float* A_log    = (const float*)d_in[9];
    const float* Dskip    = (const float*)d_in[10];
    const float* w_out    = (const float*)d_in[11];
    const float* w_ih     = (const float*)d_in[12];
    const float* w_hh     = (const float*)d_in[13];
    const float* b_ih     = (const float*)d_in[14];
    const float* b_hh     = (const float*)d_in[15];
    const float* w_fc1    = (const float*)d_in[16];
    const float* b_fc1    = (const float*)d_in[17];
    const float* w_fc2    = (const float*)d_in[18];
    const float* b_fc2    = (const float*)d_in[19];
    float* outp = (float*)d_out;

    float* ws = (float*)d_ws;
    size_t off = 0;
    float* u0   = ws + off; off += 8388608;   // later reused as yg
    float* zb   = ws + off; off += 8388608;   // later xg low half
    float* uc   = ws + off; off += 8388608;   // later xg high half
    float* dtb  = ws + off; off += 8388608;
    float* Bm   = ws + off; off += 524288;
    float* Cm   = ws + off; off += 524288;
    float* Ab   = ws + off; off += 4096;
    float* Minp = ws + off; off += 6144;
    float* cinp = ws + off; off += 512;
    float* M2   = ws + off; off += 131072;
    float* c2   = ws + off; off += 512;
    float* h0end = ws + off; off += 2097152;
    float* Ssum  = ws + off; off += 131072;
    float* hinit = ws + off; off += 2097152;
    float* yg = u0;     // alias: u0 dead after conv
    float* xg = zb;     // alias: spans zb+uc (both dead after ssm_p3)

    k_pre<<<556, 256, 0, stream>>>(w_proj, b_proj, w_inproj, A_log, w_ih, w_out,
                                   b_ih, b_hh, Ab, Minp, cinp, M2, c2);
    k_inproj<<<65536, 256, 0, stream>>>(x, Minp, cinp, u0, zb);
    k_conv<<<32768, 256, 0, stream>>>(u0, conv_w, conv_b, uc);
    k_xproj<<<32768, 256, 0, stream>>>(uc, w_xproj, w_dt, b_dt, dtb, Bm, Cm);
    k_ssm_p1<<<512, 256, 0, stream>>>(dtb, uc, Bm, Ab, h0end, Ssum);
    k_ssm_p2<<<512, 256, 0, stream>>>(h0end, Ssum, Ab, hinit);
    k_ssm_p3<<<512, 256, 0, stream>>>(dtb, uc, zb, Bm, Cm, Ab, Dskip, hinit, yg);
    k_xg<<<2048, 256, 0, stream>>>(yg, M2, c2, xg);
    k_lstm<<<32, 512, 0, stream>>>(xg, w_hh, w_fc1, b_fc1, w_fc2, b_fc2, outp);
}